// Round 1
// baseline (466.406 us; speedup 1.0000x reference)
//
#include <hip/hip_runtime.h>
#include <hip/hip_bf16.h>

// ---------------------------------------------------------------------------
// CausalSelfAttention (B=2,T=2048,C=2048,H=16,KVH=4,HD=128) on gfx950.
// Pipeline: cvt(x) ; transpose+cvt(wq,wk,wv,wo) ; GEMM->qkv ; rope+rms ;
//           flash-attn ; GEMM->out.  All MFMA 16x16x32 bf16, f32 accum.
// ---------------------------------------------------------------------------

using bf16 = __bf16;
typedef __bf16 bf16x8 __attribute__((ext_vector_type(8)));
typedef __bf16 bf16x4 __attribute__((ext_vector_type(4)));
typedef float  f32x4  __attribute__((ext_vector_type(4)));

__device__ __forceinline__ void gload_lds16(const void* g, void* l) {
  // async global->LDS, 16B/lane; LDS dest is wave-uniform base + lane*16
  __builtin_amdgcn_global_load_lds(
      (const __attribute__((address_space(1))) unsigned int*)g,
      (__attribute__((address_space(3))) unsigned int*)l, 16, 0, 0);
}

// --------------------------- elementwise convert ---------------------------
__global__ __launch_bounds__(256) void k_cvt_bf16(const float* __restrict__ src,
                                                  bf16* __restrict__ dst) {
  const int i = blockIdx.x * 256 + threadIdx.x;   // grid sized exactly
  f32x4 v = ((const f32x4*)src)[i];
  bf16x4 o;
  o[0] = (bf16)v[0]; o[1] = (bf16)v[1]; o[2] = (bf16)v[2]; o[3] = (bf16)v[3];
  ((bf16x4*)dst)[i] = o;
}

// ----------------------- transpose + convert (weights) ---------------------
// src: (R,C) f32 row-major -> dst: (C,R) bf16 row-major.  R,C multiples of 32.
__global__ __launch_bounds__(256) void k_transpose_cvt(const float* __restrict__ src,
                                                       bf16* __restrict__ dst,
                                                       int R, int C) {
  __shared__ float tile[32][33];
  const int c0 = blockIdx.x * 32, r0 = blockIdx.y * 32;
  const int tx = threadIdx.x & 31, ty = threadIdx.x >> 5;   // 32 x 8
#pragma unroll
  for (int j = 0; j < 32; j += 8)
    tile[ty + j][tx] = src[(size_t)(r0 + ty + j) * C + c0 + tx];
  __syncthreads();
#pragma unroll
  for (int j = 0; j < 32; j += 8)
    dst[(size_t)(c0 + ty + j) * R + r0 + tx] = (bf16)tile[tx][ty + j];
}

// --------------------------------- GEMM ------------------------------------
// C(M,Ntot) = A(M,K) @ B^T   with B given as (N,K) row-major (k-major).
// 128x128 tile, BK=64, 4 waves (2x2 of 64x64), global_load_lds w/ source
// pre-swizzle, XOR-swizzled ds_read_b128 (T2).  Three B pointers allow the
// fused [wq|wk|wv] column split (block-aligned boundaries nb1/nb2).
template <bool OUT_BF16>
__global__ __launch_bounds__(256) void k_gemm(
    const bf16* __restrict__ A,
    const bf16* __restrict__ B0, const bf16* __restrict__ B1,
    const bf16* __restrict__ B2, int nb1, int nb2,
    void* __restrict__ Cout, int K, int Ntot) {
  __shared__ __align__(16) bf16 As[128 * 64];
  __shared__ __align__(16) bf16 Bs[128 * 64];
  const int nb = blockIdx.x, mb = blockIdx.y;
  const bf16* Bt; int nloc;
  if (nb < nb1)      { Bt = B0; nloc = nb; }
  else if (nb < nb2) { Bt = B1; nloc = nb - nb1; }
  else               { Bt = B2; nloc = nb - nb2; }
  const int tid = threadIdx.x;
  const int w = tid >> 6, lane = tid & 63;
  const int wm = w >> 1, wn = w & 1;
  const int sr = lane >> 3, sc = lane & 7;      // staging: 8 rows x 8 chunks
  const int l16 = lane & 15, lq = lane >> 4;
  f32x4 acc[4][4] = {};
  const bf16* Ab = A  + (size_t)(mb * 128) * K;
  const bf16* Bb = Bt + (size_t)(nloc * 128) * K;
  for (int k0 = 0; k0 < K; k0 += 64) {
#pragma unroll
    for (int it = 0; it < 4; ++it) {
      const int r  = w * 32 + it * 8 + sr;
      const int cs = (sc ^ (r & 7)) << 3;       // inverse-swizzled source col
      gload_lds16(Ab + (size_t)r * K + k0 + cs, &As[(w * 32 + it * 8) * 64]);
      gload_lds16(Bb + (size_t)r * K + k0 + cs, &Bs[(w * 32 + it * 8) * 64]);
    }
    __syncthreads();
#pragma unroll
    for (int kc = 0; kc < 2; ++kc) {
      bf16x8 af[4], bfr[4];
#pragma unroll
      for (int i = 0; i < 4; ++i) {
        const int ra = wm * 64 + i * 16 + l16;
        af[i]  = *(const bf16x8*)((const char*)As + ra * 128 +
                                  ((kc * 64 + lq * 16) ^ ((ra & 7) << 4)));
        const int rb = wn * 64 + i * 16 + l16;
        bfr[i] = *(const bf16x8*)((const char*)Bs + rb * 128 +
                                  ((kc * 64 + lq * 16) ^ ((rb & 7) << 4)));
      }
#pragma unroll
      for (int i = 0; i < 4; ++i)
#pragma unroll
        for (int j = 0; j < 4; ++j)
          acc[i][j] = __builtin_amdgcn_mfma_f32_16x16x32_bf16(af[i], bfr[j],
                                                              acc[i][j], 0, 0, 0);
    }
    __syncthreads();
  }
  // epilogue: D row = (lane>>4)*4 + reg, col = lane&15  (m89-verified)
#pragma unroll
  for (int i = 0; i < 4; ++i)
#pragma unroll
    for (int j = 0; j < 4; ++j)
#pragma unroll
      for (int e = 0; e < 4; ++e) {
        const size_t row = (size_t)mb * 128 + wm * 64 + i * 16 + lq * 4 + e;
        const size_t col = (size_t)nb * 128 + wn * 64 + j * 16 + l16;
        if (OUT_BF16) ((bf16*)Cout)[row * Ntot + col] = (bf16)acc[i][j][e];
        else          ((float*)Cout)[row * Ntot + col] = acc[i][j][e];
      }
}

// ----------------------------- RoPE + RMSnorm ------------------------------
// One wave per head-vector.  heads 0..15: q (rope+rms, *1/sqrt(128)),
// 16..19: k (rope+rms), 20..23: v (relayout to (B,KVH,D,T) transposed).
__global__ __launch_bounds__(256) void k_rope(
    const bf16* __restrict__ qkv, const float* __restrict__ cosb,
    const float* __restrict__ sinb, bf16* __restrict__ q_r,
    bf16* __restrict__ k_r, bf16* __restrict__ v_t) {
  const int wid  = blockIdx.x * 4 + (threadIdx.x >> 6);
  const int lane = threadIdx.x & 63;
  const int head = wid % 24;
  const int bt   = wid / 24;
  const int b = bt >> 11, t = bt & 2047;
  const bf16* base = qkv + (size_t)bt * 3072;
  if (head >= 20) {                       // v: copy into transposed layout
    const int kv = head - 20;
    const bf16 v1 = base[2560 + kv * 128 + lane];
    const bf16 v2 = base[2560 + kv * 128 + 64 + lane];
    const size_t o = (size_t)((b * 4 + kv) * 128);
    v_t[(o + lane) * 2048 + t]      = v1;
    v_t[(o + 64 + lane) * 2048 + t] = v2;
    return;
  }
  const int col = (head < 16) ? head * 128 : 2048 + (head - 16) * 128;
  const float x1 = (float)base[col + lane];
  const float x2 = (float)base[col + 64 + lane];
  const float c = cosb[t * 64 + lane], s = sinb[t * 64 + lane];
  const float o1 = x1 * c + x2 * s;
  const float o2 = x2 * c - x1 * s;          // -x1*sin + x2*cos
  float ss = o1 * o1 + o2 * o2;
#pragma unroll
  for (int off = 32; off >= 1; off >>= 1) ss += __shfl_xor(ss, off);
  float r = rsqrtf(ss * (1.0f / 128.0f) + 1e-5f);
  if (head < 16) {
    r *= 0.08838834764831845f;               // fold 1/sqrt(HD) into q
    const size_t o = ((size_t)(b * 16 + head) * 2048 + t) * 128;
    q_r[o + lane]      = (bf16)(o1 * r);
    q_r[o + 64 + lane] = (bf16)(o2 * r);
  } else {
    const int kv = head - 16;
    const size_t o = ((size_t)(b * 4 + kv) * 2048 + t) * 128;
    k_r[o + lane]      = (bf16)(o1 * r);
    k_r[o + 64 + lane] = (bf16)(o2 * r);
  }
}

// ------------------------------ flash attention ----------------------------
// grid: (B*H) * (T/64).  4 waves x 16 q-rows.  32-wide K/V tiles in LDS.
// K staged row-major (t,d) XOR-swizzled; V pre-transposed (d,t) XOR-swizzled.
// Online softmax per row (16-lane shfl reduce); P via padded per-wave LDS.
__global__ __launch_bounds__(256) void k_attn(
    const bf16* __restrict__ q_r, const bf16* __restrict__ k_r,
    const bf16* __restrict__ v_t, bf16* __restrict__ y) {
  __shared__ __align__(16) bf16 Ks[32 * 128];
  __shared__ __align__(16) bf16 Vt[128 * 32];
  __shared__ __align__(16) bf16 Pl[4][16 * 40];   // +8 pad: 80B rows, 16B-aligned
  const int blk = blockIdx.x;
  const int bh = blk >> 5, qb = blk & 31;
  const int b = bh >> 4, h = bh & 15;
  const int bkv = b * 4 + (h >> 2);
  const int tid = threadIdx.x, w = tid >> 6, lane = tid & 63;
  const int l16 = lane & 15, lq = lane >> 4;
  const int q0 = qb * 64, t0 = q0 + w * 16;
  bf16x8 qf[4];
  const bf16* qbase = q_r + ((size_t)bh * 2048 + t0 + l16) * 128;
#pragma unroll
  for (int kc = 0; kc < 4; ++kc)
    qf[kc] = *(const bf16x8*)(qbase + kc * 32 + lq * 8);
  f32x4 acc[8] = {};
  float mrow[4] = {-1e30f, -1e30f, -1e30f, -1e30f};
  float lrow[4] = {0.f, 0.f, 0.f, 0.f};
  const bf16* kb = k_r + (size_t)bkv * (2048 * 128);
  const bf16* vb = v_t + (size_t)bkv * (128 * 2048);
  const int nt = (q0 + 64) >> 5;
  for (int itile = 0; itile < nt; ++itile) {
    const int s0 = itile << 5;
#pragma unroll
    for (int is = 0; is < 2; ++is) {
      const int rr = (w * 2 + is) * 4 + lq;          // K rows, 16 lanes/row
      const int cs = (l16 ^ (rr & 7)) << 3;
      gload_lds16(kb + (size_t)(s0 + rr) * 128 + cs, &Ks[(w * 2 + is) * 4 * 128]);
      const int d  = (w * 2 + is) * 16 + (lane >> 2); // Vt rows, 4 lanes/row
      const int sl = (lane & 3) ^ ((d >> 1) & 3);
      gload_lds16(vb + (size_t)d * 2048 + s0 + sl * 8, &Vt[(w * 2 + is) * 16 * 32]);
    }
    __syncthreads();
    if (s0 <= t0 + 15) {                 // wave has at least one unmasked col
      f32x4 sa0 = {}, sa1 = {};
#pragma unroll
      for (int kc = 0; kc < 4; ++kc) {
        const bf16x8 kf0 = *(const bf16x8*)((const char*)Ks + l16 * 256 +
                           ((kc * 64 + lq * 16) ^ ((l16 & 7) << 4)));
        sa0 = __builtin_amdgcn_mfma_f32_16x16x32_bf16(qf[kc], kf0, sa0, 0, 0, 0);
        const int r1 = 16 + l16;
        const bf16x8 kf1 = *(const bf16x8*)((const char*)Ks + r1 * 256 +
                           ((kc * 64 + lq * 16) ^ ((r1 & 7) << 4)));
        sa1 = __builtin_amdgcn_mfma_f32_16x16x32_bf16(qf[kc], kf1, sa1, 0, 0, 0);
      }
      const bool need_mask = (s0 + 31) > t0;
      float so[4];
#pragma unroll
      for (int i = 0; i < 4; ++i) {
        const int t = t0 + lq * 4 + i;
        float v0 = sa0[i], v1 = sa1[i];
        if (need_mask) {
          if (s0 + l16 > t)      v0 = -1e30f;
          if (s0 + 16 + l16 > t) v1 = -1e30f;
        }
        float mx = fmaxf(v0, v1);
        mx = fmaxf(mx, __shfl_xor(mx, 1));
        mx = fmaxf(mx, __shfl_xor(mx, 2));
        mx = fmaxf(mx, __shfl_xor(mx, 4));
        mx = fmaxf(mx, __shfl_xor(mx, 8));
        const float mnew = fmaxf(mrow[i], mx);
        const float sc = __expf(mrow[i] - mnew);
        const float p0 = __expf(v0 - mnew);
        const float p1 = __expf(v1 - mnew);
        float rs = p0 + p1;
        rs += __shfl_xor(rs, 1); rs += __shfl_xor(rs, 2);
        rs += __shfl_xor(rs, 4); rs += __shfl_xor(rs, 8);
        lrow[i] = lrow[i] * sc + rs;
        mrow[i] = mnew;
        so[i] = sc;
        const int pr = lq * 4 + i;
        Pl[w][pr * 40 + l16]      = (bf16)p0;
        Pl[w][pr * 40 + 16 + l16] = (bf16)p1;
      }
#pragma unroll
      for (int db = 0; db < 8; ++db) {
        acc[db][0] *= so[0]; acc[db][1] *= so[1];
        acc[db][2] *= so[2]; acc[db][3] *= so[3];
      }
      const bf16x8 pa = *(const bf16x8*)(&Pl[w][l16 * 40 + lq * 8]);
#pragma unroll
      for (int db = 0; db < 8; ++db) {
        const int d  = db * 16 + l16;
        const int sl = lq ^ ((d >> 1) & 3);
        const bf16x8 vf = *(const bf16x8*)((const char*)Vt + d * 64 + sl * 16);
        acc[db] = __builtin_amdgcn_mfma_f32_16x16x32_bf16(pa, vf, acc[db], 0, 0, 0);
      }
    }
    __syncthreads();
  }
#pragma unroll
  for (int i = 0; i < 4; ++i) {
    const int t = t0 + lq * 4 + i;
    const float inv = 1.0f / lrow[i];
    bf16* yb = y + ((size_t)(b * 2048 + t) * 16 + h) * 128;
#pragma unroll
    for (int db = 0; db < 8; ++db)
      yb[db * 16 + l16] = (bf16)(acc[db][i] * inv);
  }
}

// --------------------------------- launch ----------------------------------
extern "C" void kernel_launch(void* const* d_in, const int* in_sizes, int n_in,
                              void* d_out, int out_size, void* d_ws, size_t ws_size,
                              hipStream_t stream) {
  const float* x    = (const float*)d_in[0];
  const float* cosb = (const float*)d_in[1];
  const float* sinb = (const float*)d_in[2];
  const float* wq   = (const float*)d_in[3];
  const float* wk   = (const float*)d_in[4];
  const float* wv   = (const float*)d_in[5];
  const float* wo   = (const float*)d_in[6];
  float* out = (float*)d_out;

  char* ws = (char*)d_ws;
  size_t off = 0;
  auto alloc = [&](size_t bytes) {
    char* p = ws + off; off += (bytes + 255) & ~(size_t)255; return p;
  };
  bf16* xb  = (bf16*)alloc(4096ull * 2048 * 2);   // x bf16; reused as y later
  bf16* wqT = (bf16*)alloc(2048ull * 2048 * 2);
  bf16* wkT = (bf16*)alloc(512ull  * 2048 * 2);
  bf16* wvT = (bf16*)alloc(512ull  * 2048 * 2);
  bf16* woT = (bf16*)alloc(2048ull * 2048 * 2);
  bf16* qkv = (bf16*)alloc(4096ull * 3072 * 2);
  bf16* q_r = (bf16*)alloc(4096ull * 2048 * 2);
  bf16* k_r = (bf16*)alloc(4096ull * 512  * 2);
  bf16* v_t = (bf16*)alloc(4096ull * 512  * 2);
  bf16* y   = xb;                                  // xb dead after gemm_qkv

  k_cvt_bf16<<<(4096 * 2048 / 4) / 256, 256, 0, stream>>>(x, xb);
  k_transpose_cvt<<<dim3(64, 64), 256, 0, stream>>>(wq, wqT, 2048, 2048);
  k_transpose_cvt<<<dim3(16, 64), 256, 0, stream>>>(wk, wkT, 2048, 512);
  k_transpose_cvt<<<dim3(16, 64), 256, 0, stream>>>(wv, wvT, 2048, 512);
  k_transpose_cvt<<<dim3(64, 64), 256, 0, stream>>>(wo, woT, 2048, 2048);
  // qkv = x @ [wq|wk|wv]   (col blocks: 0..15 -> q, 16..19 -> k, 20..23 -> v)
  k_gemm<true><<<dim3(24, 32), 256, 0, stream>>>(xb, wqT, wkT, wvT, 16, 20,
                                                 qkv, 2048, 3072);
  k_rope<<<24576, 256, 0, stream>>>(qkv, cosb, sinb, q_r, k_r, v_t);
  k_attn<<<1024, 256, 0, stream>>>(q_r, k_r, v_t, y);
  // out = y @ wo
  k_gemm<false><<<dim3(16, 32), 256, 0, stream>>>(y, woT, woT, woT, 100, 200,
                                                  out, 2048, 2048);
}

// Round 7
// 335.669 us; speedup vs baseline: 1.3895x; 1.3895x over previous
//
#include <hip/hip_runtime.h>
#include <hip/hip_bf16.h>

// ---------------------------------------------------------------------------
// CausalSelfAttention (B=2,T=2048,C=2048,H=16,KVH=4,HD=128) on gfx950.
// Pipeline: cvt(x) ; transpose+cvt(wq,wk,wv,wo) ; GEMM->qkv ; rope+rms ;
//           flash-attn (swapped-QK^T, reg softmax) ; GEMM->out.
// ---------------------------------------------------------------------------

using bf16 = __bf16;
typedef __bf16 bf16x8 __attribute__((ext_vector_type(8)));
typedef __bf16 bf16x4 __attribute__((ext_vector_type(4)));
typedef float  f32x4  __attribute__((ext_vector_type(4)));

__device__ __forceinline__ void gload_lds16(const void* g, void* l) {
  __builtin_amdgcn_global_load_lds(
      (const __attribute__((address_space(1))) unsigned int*)g,
      (__attribute__((address_space(3))) unsigned int*)l, 16, 0, 0);
}

__device__ __forceinline__ unsigned pack2(float a, float b) {
  // u32 = [bf16(b) | bf16(a)]  (low half = a)
  unsigned short ua = __builtin_bit_cast(unsigned short, (bf16)a);
  unsigned short ub = __builtin_bit_cast(unsigned short, (bf16)b);
  return ((unsigned)ub << 16) | ua;
}

// --------------------------- elementwise convert ---------------------------
__global__ __launch_bounds__(256) void k_cvt_bf16(const float* __restrict__ src,
                                                  bf16* __restrict__ dst) {
  const int i = blockIdx.x * 256 + threadIdx.x;
  f32x4 v = ((const f32x4*)src)[i];
  bf16x4 o;
  o[0] = (bf16)v[0]; o[1] = (bf16)v[1]; o[2] = (bf16)v[2]; o[3] = (bf16)v[3];
  ((bf16x4*)dst)[i] = o;
}

// ----------------------- transpose + convert (weights) ---------------------
__global__ __launch_bounds__(256) void k_transpose_cvt(const float* __restrict__ src,
                                                       bf16* __restrict__ dst,
                                                       int R, int C) {
  __shared__ float tile[32][33];
  const int c0 = blockIdx.x * 32, r0 = blockIdx.y * 32;
  const int tx = threadIdx.x & 31, ty = threadIdx.x >> 5;
#pragma unroll
  for (int j = 0; j < 32; j += 8)
    tile[ty + j][tx] = src[(size_t)(r0 + ty + j) * C + c0 + tx];
  __syncthreads();
#pragma unroll
  for (int j = 0; j < 32; j += 8)
    dst[(size_t)(c0 + ty + j) * R + r0 + tx] = (bf16)tile[tx][ty + j];
}

// --------------------------------- GEMM ------------------------------------
template <bool OUT_BF16>
__global__ __launch_bounds__(256) void k_gemm(
    const bf16* __restrict__ A,
    const bf16* __restrict__ B0, const bf16* __restrict__ B1,
    const bf16* __restrict__ B2, int nb1, int nb2,
    void* __restrict__ Cout, int K, int Ntot) {
  __shared__ __align__(16) bf16 As[128 * 64];
  __shared__ __align__(16) bf16 Bs[128 * 64];
  const int nb = blockIdx.x, mb = blockIdx.y;
  const bf16* Bt; int nloc;
  if (nb < nb1)      { Bt = B0; nloc = nb; }
  else if (nb < nb2) { Bt = B1; nloc = nb - nb1; }
  else               { Bt = B2; nloc = nb - nb2; }
  const int tid = threadIdx.x;
  const int w = tid >> 6, lane = tid & 63;
  const int wm = w >> 1, wn = w & 1;
  const int sr = lane >> 3, sc = lane & 7;
  const int l16 = lane & 15, lq = lane >> 4;
  f32x4 acc[4][4] = {};
  const bf16* Ab = A  + (size_t)(mb * 128) * K;
  const bf16* Bb = Bt + (size_t)(nloc * 128) * K;
  for (int k0 = 0; k0 < K; k0 += 64) {
#pragma unroll
    for (int it = 0; it < 4; ++it) {
      const int r  = w * 32 + it * 8 + sr;
      const int cs = (sc ^ (r & 7)) << 3;
      gload_lds16(Ab + (size_t)r * K + k0 + cs, &As[(w * 32 + it * 8) * 64]);
      gload_lds16(Bb + (size_t)r * K + k0 + cs, &Bs[(w * 32 + it * 8) * 64]);
    }
    __syncthreads();
#pragma unroll
    for (int kc = 0; kc < 2; ++kc) {
      bf16x8 af[4], bfr[4];
#pragma unroll
      for (int i = 0; i < 4; ++i) {
        const int ra = wm * 64 + i * 16 + l16;
        af[i]  = *(const bf16x8*)((const char*)As + ra * 128 +
                                  ((kc * 64 + lq * 16) ^ ((ra & 7) << 4)));
        const int rb = wn * 64 + i * 16 + l16;
        bfr[i] = *(const bf16x8*)((const char*)Bs + rb * 128 +
                                  ((kc * 64 + lq * 16) ^ ((rb & 7) << 4)));
      }
#pragma unroll
      for (int i = 0; i < 4; ++i)
#pragma unroll
        for (int j = 0; j < 4; ++j)
          acc[i][j] = __builtin_amdgcn_mfma_f32_16x16x32_bf16(af[i], bfr[j],
                                                              acc[i][j], 0, 0, 0);
    }
    __syncthreads();
  }
#pragma unroll
  for (int i = 0; i < 4; ++i)
#pragma unroll
    for (int j = 0; j < 4; ++j)
#pragma unroll
      for (int e = 0; e < 4; ++e) {
        const size_t row = (size_t)mb * 128 + wm * 64 + i * 16 + lq * 4 + e;
        const size_t col = (size_t)nb * 128 + wn * 64 + j * 16 + l16;
        if (OUT_BF16) ((bf16*)Cout)[row * Ntot + col] = (bf16)acc[i][j][e];
        else          ((float*)Cout)[row * Ntot + col] = acc[i][j][e];
      }
}

// ----------------------------- RoPE + RMSnorm ------------------------------
__global__ __launch_bounds__(256) void k_rope(
    const bf16* __restrict__ qkv, const float* __restrict__ cosb,
    const float* __restrict__ sinb, bf16* __restrict__ q_r,
    bf16* __restrict__ k_r, bf16* __restrict__ v_t) {
  const int wid  = blockIdx.x * 4 + (threadIdx.x >> 6);
  const int lane = threadIdx.x & 63;
  const int head = wid % 24;
  const int bt   = wid / 24;
  const int b = bt >> 11, t = bt & 2047;
  const bf16* base = qkv + (size_t)bt * 3072;
  if (head >= 20) {
    const int kv = head - 20;
    const bf16 v1 = base[2560 + kv * 128 + lane];
    const bf16 v2 = base[2560 + kv * 128 + 64 + lane];
    const size_t o = (size_t)((b * 4 + kv) * 128);
    v_t[(o + lane) * 2048 + t]      = v1;
    v_t[(o + 64 + lane) * 2048 + t] = v2;
    return;
  }
  const int col = (head < 16) ? head * 128 : 2048 + (head - 16) * 128;
  const float x1 = (float)base[col + lane];
  const float x2 = (float)base[col + 64 + lane];
  const float c = cosb[t * 64 + lane], s = sinb[t * 64 + lane];
  const float o1 = x1 * c + x2 * s;
  const float o2 = x2 * c - x1 * s;
  float ss = o1 * o1 + o2 * o2;
#pragma unroll
  for (int off = 32; off >= 1; off >>= 1) ss += __shfl_xor(ss, off);
  float r = rsqrtf(ss * (1.0f / 128.0f) + 1e-5f);
  if (head < 16) {
    r *= 0.08838834764831845f;
    const size_t o = ((size_t)(b * 16 + head) * 2048 + t) * 128;
    q_r[o + lane]      = (bf16)(o1 * r);
    q_r[o + 64 + lane] = (bf16)(o2 * r);
  } else {
    const int kv = head - 16;
    const size_t o = ((size_t)(b * 4 + kv) * 2048 + t) * 128;
    k_r[o + lane]      = (bf16)(o1 * r);
    k_r[o + 64 + lane] = (bf16)(o2 * r);
  }
}

// ------------------------------ flash attention ----------------------------
// Swapped QK^T: st = mfma(K_frag, Q_frag) -> S^T, lane owns one q-row.
// 4 waves x 32 q-rows (two 16-row halves, fragment reuse), KVBLK=64,
// double-buffered K/V in LDS, P redistributed via shfl (no LDS), defer-max.
__global__ __launch_bounds__(256, 2) void k_attn(
    const bf16* __restrict__ q_r, const bf16* __restrict__ k_r,
    const bf16* __restrict__ v_t, bf16* __restrict__ y) {
  __shared__ __align__(16) bf16 Ks[2][64 * 128];   // [buf][kv][d]
  __shared__ __align__(16) bf16 Vt[2][128 * 64];   // [buf][d][kv]
  const int blkid = blockIdx.x;
  // bh packed so each XCD (blk%8) keeps 4 heads' KV in its L2; long q-blocks
  // (qb 8..15) dispatched first, short second -> balanced per-CU pairs.
  const int bh = (blkid & 7) * 4 + ((blkid >> 3) & 3);
  const int g  = blkid >> 5;
  const int qb = (blkid < 256) ? (15 - g) : (g - 8);
  const int b = bh >> 4, h = bh & 15;
  const int bkv = b * 4 + (h >> 2);
  const int tid = threadIdx.x, w = tid >> 6, lane = tid & 63;
  const int l16 = lane & 15, lq = lane >> 4;
  const int swz = (l16 & 7) << 4;
  const int q0 = qb * 128, t0A = q0 + w * 32;
  const int nt = 2 * qb + 2;
  const bf16* kb = k_r + (size_t)bkv * (2048 * 128);
  const bf16* vb = v_t + (size_t)bkv * (128 * 2048);

  // Q fragments (B-operand layout): Q[t0+l16][32kc+8lq+j]
  bf16x8 qfA[4], qfB[4];
  const bf16* qbase = q_r + ((size_t)bh * 2048 + t0A + l16) * 128;
#pragma unroll
  for (int kc = 0; kc < 4; ++kc) {
    qfA[kc] = *(const bf16x8*)(qbase + 32 * kc + 8 * lq);
    qfB[kc] = *(const bf16x8*)(qbase + 16 * 128 + 32 * kc + 8 * lq);
  }

  f32x4 accA[8] = {}, accB[8] = {};
  float mA = -1e29f, mB = -1e29f, lA = 0.f, lB = 0.f;

  auto stage = [&](int buf, int s0n) {
#pragma unroll
    for (int it = 0; it < 4; ++it) {
      const int rK = w * 16 + it * 4 + (lane >> 4);
      gload_lds16(kb + (size_t)(s0n + rK) * 128 + (((lane & 15) ^ (rK & 7)) << 3),
                  &Ks[buf][(w * 16 + it * 4) * 128]);
      const int rV = w * 32 + it * 8 + (lane >> 3);
      gload_lds16(vb + (size_t)rV * 2048 + s0n + (((lane & 7) ^ (rV & 7)) << 3),
                  &Vt[buf][(w * 32 + it * 8) * 64]);
    }
  };

  stage(0, 0);
  asm volatile("s_waitcnt vmcnt(0)" ::: "memory");
  __syncthreads();

  for (int t = 0; t < nt; ++t) {
    if (t + 1 < nt) stage((t + 1) & 1, (t + 1) * 64);
    const int s0 = t * 64;
    const int buf = t & 1;
    if (s0 <= t0A + 31) {              // wave participates in this tile
      // ---- QK^T (swapped): st[n] = K(16kv x 32d) * Q^T -> S^T ----
      f32x4 stA[4] = {}, stB[4] = {};
#pragma unroll
      for (int kc = 0; kc < 4; ++kc)
#pragma unroll
        for (int n = 0; n < 4; ++n) {
          const int rk = 16 * n + l16;
          const bf16x8 kf = *(const bf16x8*)((const char*)&Ks[buf][0] +
                             rk * 256 + ((64 * kc + 16 * lq) ^ swz));
          stA[n] = __builtin_amdgcn_mfma_f32_16x16x32_bf16(kf, qfA[kc], stA[n], 0, 0, 0);
          stB[n] = __builtin_amdgcn_mfma_f32_16x16x32_bf16(kf, qfB[kc], stB[n], 0, 0, 0);
        }
      const int qgA = t0A + l16, qgB = qgA + 16;
      if (s0 + 63 > t0A) {             // diagonal: apply causal mask
#pragma unroll
        for (int n = 0; n < 4; ++n)
#pragma unroll
          for (int e = 0; e < 4; ++e) {
            const int kvg = s0 + 16 * n + 4 * lq + e;
            if (kvg > qgA) stA[n][e] = -1e30f;
            if (kvg > qgB) stB[n][e] = -1e30f;
          }
      }
      // ---- online softmax, per-lane q-row ----
      float mxA = -1e30f, mxB = -1e30f;
#pragma unroll
      for (int n = 0; n < 4; ++n)
#pragma unroll
        for (int e = 0; e < 4; ++e) {
          mxA = fmaxf(mxA, stA[n][e]);
          mxB = fmaxf(mxB, stB[n][e]);
        }
      mxA = fmaxf(mxA, __shfl_xor(mxA, 16)); mxA = fmaxf(mxA, __shfl_xor(mxA, 32));
      mxB = fmaxf(mxB, __shfl_xor(mxB, 16)); mxB = fmaxf(mxB, __shfl_xor(mxB, 32));
      const bool small = (mxA <= mA + 8.f) && (mxB <= mB + 8.f);
      if (!__all(small)) {             // rescale (deferred-max, THR=8)
        const float mnA = fmaxf(mA, mxA), mnB = fmaxf(mB, mxB);
        const float scA = __expf(mA - mnA), scB = __expf(mB - mnB);
        mA = mnA; mB = mnB; lA *= scA; lB *= scB;
#pragma unroll
        for (int d2 = 0; d2 < 8; ++d2) { accA[d2] *= scA; accB[d2] *= scB; }
      }
      float rsA = 0.f, rsB = 0.f;
#pragma unroll
      for (int n = 0; n < 4; ++n)
#pragma unroll
        for (int e = 0; e < 4; ++e) {
          stA[n][e] = __expf(stA[n][e] - mA); rsA += stA[n][e];
          stB[n][e] = __expf(stB[n][e] - mB); rsB += stB[n][e];
        }
      rsA += __shfl_xor(rsA, 16); rsA += __shfl_xor(rsA, 32); lA += rsA;
      rsB += __shfl_xor(rsB, 16); rsB += __shfl_xor(rsB, 32); lB += rsB;
      // ---- pack P to bf16 pairs: P2[n*2+h] holds kv = 16n+4lq+2h+{0,1} ----
      unsigned pA2[8], pB2[8];
#pragma unroll
      for (int n = 0; n < 4; ++n) {
        pA2[n * 2 + 0] = pack2(stA[n][0], stA[n][1]);
        pA2[n * 2 + 1] = pack2(stA[n][2], stA[n][3]);
        pB2[n * 2 + 0] = pack2(stB[n][0], stB[n][1]);
        pB2[n * 2 + 1] = pack2(stB[n][2], stB[n][3]);
      }
      // ---- redistribute P^T to PV B-operand, then PV MFMAs ----
      const int src0 = l16 | ((((lq & 1) << 1) | 0) << 4);
      const int src1 = l16 | ((((lq & 1) << 1) | 1) << 4);
      const bool selhi = (lq & 2);
#pragma unroll
      for (int c = 0; c < 2; ++c) {
        union { unsigned u[4]; bf16x8 v; } wA, wB;
        {
          unsigned a0 = __shfl((int)pA2[(2*c)*2+0], src0), b0 = __shfl((int)pA2[(2*c+1)*2+0], src0);
          unsigned a1 = __shfl((int)pA2[(2*c)*2+1], src0), b1 = __shfl((int)pA2[(2*c+1)*2+1], src0);
          unsigned a2 = __shfl((int)pA2[(2*c)*2+0], src1), b2 = __shfl((int)pA2[(2*c+1)*2+0], src1);
          unsigned a3 = __shfl((int)pA2[(2*c)*2+1], src1), b3 = __shfl((int)pA2[(2*c+1)*2+1], src1);
          wA.u[0] = selhi ? b0 : a0; wA.u[1] = selhi ? b1 : a1;
          wA.u[2] = selhi ? b2 : a2; wA.u[3] = selhi ? b3 : a3;
        }
        {
          unsigned a0 = __shfl((int)pB2[(2*c)*2+0], src0), b0 = __shfl((int)pB2[(2*c+1)*2+0], src0);
          unsigned a1 = __shfl((int)pB2[(2*c)*2+1], src0), b1 = __shfl((int)pB2[(2*c+1)*2+1], src0);
          unsigned a2 = __shfl((int)pB2[(2*c)*2+0], src1), b2 = __shfl((int)pB2[(2*c+1)*2+0], src1);
          unsigned a3 = __shfl((int)pB2[(2*c)*2+1], src1), b3 = __shfl((int)pB2[(2*c+1)*2+1], src1);
          wB.u[0] = selhi ? b0 : a0; wB.u[1] = selhi ? b1 : a1;
          wB.u[2] = selhi ? b2 : a2; wB.u[3] = selhi ? b3 : a3;
        }
#pragma unroll
        for (int dblk = 0; dblk < 8; ++dblk) {
          const int rv = 16 * dblk + l16;
          const bf16x8 vf = *(const bf16x8*)((const char*)&Vt[buf][0] +
                             rv * 128 + ((64 * c + 16 * lq) ^ swz));
          accA[dblk] = __builtin_amdgcn_mfma_f32_16x16x32_bf16(vf, wA.v, accA[dblk], 0, 0, 0);
          accB[dblk] = __builtin_amdgcn_mfma_f32_16x16x32_bf16(vf, wB.v, accB[dblk], 0, 0, 0);
        }
      }
    }
    asm volatile("s_waitcnt vmcnt(0)" ::: "memory");
    __syncthreads();
  }

  // ---- epilogue: O^T[d = 16dblk+4lq+e][q = t0h+l16] ----
  const float invA = 1.f / lA, invB = 1.f / lB;
  bf16* yA = y + (((size_t)b * 2048 + t0A + l16) * 16 + h) * 128;
  bf16* yB = yA + (size_t)16 * 2048;   // +16 q-rows
#pragma unroll
  for (int dblk = 0; dblk < 8; ++dblk) {
    unsigned loA = pack2(accA[dblk][0] * invA, accA[dblk][1] * invA);
    unsigned hiA = pack2(accA[dblk][2] * invA, accA[dblk][3] * invA);
    *(uint2*)(yA + 16 * dblk + 4 * lq) = make_uint2(loA, hiA);
    unsigned loB = pack2(accB[dblk][0] * invB, accB[dblk][1] * invB);
    unsigned hiB = pack2(accB[dblk][2] * invB, accB[dblk][3] * invB);
    *(uint2*)(yB + 16 * dblk + 4 * lq) = make_uint2(loB, hiB);
  }
}

// --------------------------------- launch ----------------------------------
extern "C" void kernel_launch(void* const* d_in, const int* in_sizes, int n_in,
                              void* d_out, int out_size, void* d_ws, size_t ws_size,
                              hipStream_t stream) {
  const float* x    = (const float*)d_in[0];
  const float* cosb = (const float*)d_in[1];
  const float* sinb = (const float*)d_in[2];
  const float* wq   = (const float*)d_in[3];
  const float* wk   = (const float*)d_in[4];
  const float* wv   = (const float*)d_in[5];
  const float* wo   = (const float*)d_in[6];
  float* out = (float*)d_out;

  char* ws = (char*)d_ws;
  size_t off = 0;
  auto alloc = [&](size_t bytes) {
    char* p = ws + off; off += (bytes + 255) & ~(size_t)255; return p;
  };
  bf16* xb  = (bf16*)alloc(4096ull * 2048 * 2);
  bf16* wqT = (bf16*)alloc(2048ull * 2048 * 2);
  bf16* wkT = (bf16*)alloc(512ull  * 2048 * 2);
  bf16* wvT = (bf16*)alloc(512ull  * 2048 * 2);
  bf16* woT = (bf16*)alloc(2048ull * 2048 * 2);
  bf16* qkv = (bf16*)alloc(4096ull * 3072 * 2);
  bf16* q_r = (bf16*)alloc(4096ull * 2048 * 2);
  bf16* k_r = (bf16*)alloc(4096ull * 512  * 2);
  bf16* v_t = (bf16*)alloc(4096ull * 512  * 2);
  bf16* y   = xb;                                  // xb dead after gemm_qkv

  k_cvt_bf16<<<(4096 * 2048 / 4) / 256, 256, 0, stream>>>(x, xb);
  k_transpose_cvt<<<dim3(64, 64), 256, 0, stream>>>(wq, wqT, 2048, 2048);
  k_transpose_cvt<<<dim3(16, 64), 256, 0, stream>>>(wk, wkT, 2048, 512);
  k_transpose_cvt<<<dim3(16, 64), 256, 0, stream>>>(wv, wvT, 2048, 512);
  k_transpose_cvt<<<dim3(64, 64), 256, 0, stream>>>(wo, woT, 2048, 2048);
  k_gemm<true><<<dim3(24, 32), 256, 0, stream>>>(xb, wqT, wkT, wvT, 16, 20,
                                                 qkv, 2048, 3072);
  k_rope<<<24576, 256, 0, stream>>>(qkv, cosb, sinb, q_r, k_r, v_t);
  k_attn<<<512, 256, 0, stream>>>(q_r, k_r, v_t, y);
  k_gemm<false><<<dim3(16, 32), 256, 0, stream>>>(y, woT, woT, woT, 100, 200,
                                                  out, 2048, 2048);
}